// Round 1
// baseline (8468.780 us; speedup 1.0000x reference)
//
#include <hip/hip_runtime.h>

#define NNODES 50000
#define DIM 128

// ---------------------------------------------------------------------------
// Scatter-add aggregation: agg[dst[e], :] += x[src[e], :]
// One thread per (edge, float4-chunk): 32 chunks per 128-float row.
// ---------------------------------------------------------------------------
__global__ __launch_bounds__(256) void k_scatter_add(
    const float* __restrict__ x, const int* __restrict__ src,
    const int* __restrict__ dst, float* __restrict__ agg, int n_edges)
{
    int idx = blockIdx.x * blockDim.x + threadIdx.x;
    int e = idx >> 5;
    if (e >= n_edges) return;
    int d4 = idx & 31;
    int s = src[e];
    int t = dst[e];
    float4 v = reinterpret_cast<const float4*>(x)[(size_t)s * 32 + d4];
    float* p = agg + (size_t)t * DIM + d4 * 4;
    atomicAdd(p + 0, v.x);
    atomicAdd(p + 1, v.y);
    atomicAdd(p + 2, v.z);
    atomicAdd(p + 3, v.w);
}

// ---------------------------------------------------------------------------
// Fused dual GEMM: C[n,h] = act( dot(A[n,:],Wa[h,:]) + dot(B[n,:],Wb[h,:]) + bias[h] )
// A,B: [n_nodes, 128] row-major.  Wa,Wb: [BN, 128] row-major (PyG [out,in]).
// Block tile: 64 nodes x BN outputs, BK=32 K-chunks, 256 threads.
// Thread (r = tid&15, c = tid>>4) computes 4 nodes x (BN/16) outputs.
// ---------------------------------------------------------------------------
template <int BN, bool RELU>
__global__ __launch_bounds__(256) void k_dual_gemm(
    const float* __restrict__ A, const float* __restrict__ B,
    const float* __restrict__ Wa, const float* __restrict__ Wb,
    const float* __restrict__ bias, float* __restrict__ C, int n_nodes)
{
    constexpr int BM = 64, BK = 32;
    constexpr int TM = 4;
    constexpr int TN = BN / 16;            // 8 (BN=128) or 4 (BN=64)
    __shared__ float As[BM][BK + 1];       // +1 pad: 2-way max on reads (free)
    __shared__ float Ws[BK][BN];           // staged transposed: Ws[k][h]

    const int tid = threadIdx.x;
    const int r = tid & 15;                // node group (4 nodes each)
    const int c = tid >> 4;                // column group (TN cols each)
    const int n0 = blockIdx.x * BM;

    float acc[TM][TN];
#pragma unroll
    for (int i = 0; i < TM; ++i)
#pragma unroll
        for (int j = 0; j < TN; ++j) acc[i][j] = 0.f;

    // A-tile load mapping: each thread loads 8 consecutive floats
    const int lm = tid >> 2;               // row within tile (0..63)
    const int lk = (tid & 3) * 8;          // col within K-chunk
    // W-tile load mapping: WL floats per thread along d for one h
    constexpr int WL = (BK * BN) / 256;    // 16 or 8
    constexpr int KSPLIT = BK / WL;        // 2 or 4
    const int wh = tid / KSPLIT;           // h index (0..BN-1)
    const int wk = (tid % KSPLIT) * WL;    // k start

#pragma unroll
    for (int half = 0; half < 2; ++half) {
        const float* __restrict__ Ain = half ? B : A;
        const float* __restrict__ Win = half ? Wb : Wa;
#pragma unroll
        for (int kb = 0; kb < DIM; kb += BK) {
            __syncthreads();
            // stage A tile
            {
                int n = n0 + lm;
                float4 v0, v1;
                if (n < n_nodes) {
                    const float4* gp =
                        reinterpret_cast<const float4*>(Ain + (size_t)n * DIM + kb + lk);
                    v0 = gp[0];
                    v1 = gp[1];
                } else {
                    v0 = make_float4(0.f, 0.f, 0.f, 0.f);
                    v1 = v0;
                }
                As[lm][lk + 0] = v0.x; As[lm][lk + 1] = v0.y;
                As[lm][lk + 2] = v0.z; As[lm][lk + 3] = v0.w;
                As[lm][lk + 4] = v1.x; As[lm][lk + 5] = v1.y;
                As[lm][lk + 6] = v1.z; As[lm][lk + 7] = v1.w;
            }
            // stage W tile (transposed)
            {
#pragma unroll
                for (int i = 0; i < WL; i += 4) {
                    float4 v = *reinterpret_cast<const float4*>(
                        Win + (size_t)wh * DIM + kb + wk + i);
                    Ws[wk + i + 0][wh] = v.x;
                    Ws[wk + i + 1][wh] = v.y;
                    Ws[wk + i + 2][wh] = v.z;
                    Ws[wk + i + 3][wh] = v.w;
                }
            }
            __syncthreads();
            // compute
#pragma unroll
            for (int d = 0; d < BK; ++d) {
                float a[TM];
#pragma unroll
                for (int i = 0; i < TM; ++i) a[i] = As[r * TM + i][d];
                float w[TN];
#pragma unroll
                for (int j = 0; j < TN; j += 4) {
                    float4 wv = *reinterpret_cast<const float4*>(&Ws[d][c * TN + j]);
                    w[j + 0] = wv.x; w[j + 1] = wv.y;
                    w[j + 2] = wv.z; w[j + 3] = wv.w;
                }
#pragma unroll
                for (int i = 0; i < TM; ++i)
#pragma unroll
                    for (int j = 0; j < TN; ++j) acc[i][j] += a[i] * w[j];
            }
        }
    }

    // epilogue: bias + optional relu, vectorized store
    float bv[TN];
#pragma unroll
    for (int j = 0; j < TN; ++j) bv[j] = bias[c * TN + j];
#pragma unroll
    for (int i = 0; i < TM; ++i) {
        int n = n0 + r * TM + i;
        if (n >= n_nodes) continue;
#pragma unroll
        for (int j = 0; j < TN; j += 4) {
            float4 o;
            o.x = acc[i][j + 0] + bv[j + 0];
            o.y = acc[i][j + 1] + bv[j + 1];
            o.z = acc[i][j + 2] + bv[j + 2];
            o.w = acc[i][j + 3] + bv[j + 3];
            if (RELU) {
                o.x = fmaxf(o.x, 0.f); o.y = fmaxf(o.y, 0.f);
                o.z = fmaxf(o.z, 0.f); o.w = fmaxf(o.w, 0.f);
            }
            *reinterpret_cast<float4*>(C + (size_t)n * BN + c * TN + j) = o;
        }
    }
}

extern "C" void kernel_launch(void* const* d_in, const int* in_sizes, int n_in,
                              void* d_out, int out_size, void* d_ws, size_t ws_size,
                              hipStream_t stream) {
    const float* x       = (const float*)d_in[0];
    const int*   ei      = (const int*)d_in[1];
    const float* W_rel1  = (const float*)d_in[2];
    const float* W_root1 = (const float*)d_in[3];
    const float* b1      = (const float*)d_in[4];
    const float* W_rel2  = (const float*)d_in[5];
    const float* W_root2 = (const float*)d_in[6];
    const float* b2      = (const float*)d_in[7];

    const int n_edges = in_sizes[1] / 2;
    const int* src = ei;
    const int* dst = ei + n_edges;

    float* agg = (float*)d_ws;                        // [NNODES,128] 25.6 MB (reused)
    float* t   = agg + (size_t)NNODES * DIM;          // [NNODES,128] 25.6 MB
    float* out = (float*)d_out;                       // [NNODES,64]

    const size_t agg_bytes = (size_t)NNODES * DIM * sizeof(float);
    const int scat_blocks = (n_edges * 32 + 255) / 256;
    const int gemm_blocks = (NNODES + 63) / 64;

    // ---- layer 1 ----
    hipMemsetAsync(agg, 0, agg_bytes, stream);
    k_scatter_add<<<scat_blocks, 256, 0, stream>>>(x, src, dst, agg, n_edges);
    k_dual_gemm<128, true><<<gemm_blocks, 256, 0, stream>>>(
        agg, x, W_rel1, W_root1, b1, t, NNODES);

    // ---- layer 2 ----
    hipMemsetAsync(agg, 0, agg_bytes, stream);
    k_scatter_add<<<scat_blocks, 256, 0, stream>>>(t, src, dst, agg, n_edges);
    k_dual_gemm<64, false><<<gemm_blocks, 256, 0, stream>>>(
        agg, t, W_rel2, W_root2, b2, out, NNODES);
}

// Round 2
// 2875.705 us; speedup vs baseline: 2.9449x; 2.9449x over previous
//
#include <hip/hip_runtime.h>

#define NNODES 50000
#define DIM 128

// ---------------------------------------------------------------------------
// Scatter-add aggregation: agg[dst[e], :] += x[src[e], :]
// One thread per (edge, float4-chunk): 32 chunks per 128-float row.
// ---------------------------------------------------------------------------
__global__ __launch_bounds__(256) void k_scatter_add(
    const float* __restrict__ x, const int* __restrict__ src,
    const int* __restrict__ dst, float* __restrict__ agg, int n_edges)
{
    int idx = blockIdx.x * blockDim.x + threadIdx.x;
    int e = idx >> 5;
    if (e >= n_edges) return;
    int d4 = idx & 31;
    int s = src[e];
    int t = dst[e];
    float4 v = reinterpret_cast<const float4*>(x)[(size_t)s * 32 + d4];
    float* p = agg + (size_t)t * DIM + d4 * 4;
    atomicAdd(p + 0, v.x);
    atomicAdd(p + 1, v.y);
    atomicAdd(p + 2, v.z);
    atomicAdd(p + 3, v.w);
}

// ---------------------------------------------------------------------------
// Fused dual GEMM: C[n,h] = act( dot(A[n,:],Wa[h,:]) + dot(B[n,:],Wb[h,:]) + b[h] )
// A,B: [n_nodes, 128] row-major.  Wa,Wb: [BN, 128] row-major (PyG [out,in]).
// Block tile: 64 nodes x BN outputs, 8 K-chunks of 32 (A half then B half),
// 256 threads. Thread (r=tid&15, c=tid>>4) computes 4 nodes x (BN/16) outputs.
// NOTE: chunk loop is "#pragma unroll 1" — full unroll previously pipelined
// all 8 chunks' staging loads at once -> 256 VGPRs -> scratch spill -> 6 GB
// of HBM traffic per dispatch. Keep it serialized.
// ---------------------------------------------------------------------------
template <int BN, bool RELU>
__global__ __launch_bounds__(256) void k_dual_gemm(
    const float* __restrict__ A, const float* __restrict__ B,
    const float* __restrict__ Wa, const float* __restrict__ Wb,
    const float* __restrict__ bias, float* __restrict__ C, int n_nodes)
{
    constexpr int BM = 64, BK = 32;
    constexpr int TM = 4;
    constexpr int TN = BN / 16;            // 8 (BN=128) or 4 (BN=64)
    __shared__ float As[BM][BK + 1];       // +1 pad: 2-way max on reads (free)
    __shared__ float Ws[BK][BN];           // staged transposed: Ws[k][h]

    const int tid = threadIdx.x;
    const int r = tid & 15;                // node group (4 nodes each)
    const int c = tid >> 4;                // column group (TN cols each)
    const int n0 = blockIdx.x * BM;

    float acc[TM][TN];
#pragma unroll
    for (int i = 0; i < TM; ++i)
#pragma unroll
        for (int j = 0; j < TN; ++j) acc[i][j] = 0.f;

    // A-tile load mapping: each thread loads 8 consecutive floats
    const int lm = tid >> 2;               // row within tile (0..63)
    const int lk = (tid & 3) * 8;          // col within K-chunk
    // W-tile load mapping: WL floats per thread along d for one h
    constexpr int WL = (BK * BN) / 256;    // 16 or 8
    constexpr int KSPLIT = BK / WL;        // 2 or 4
    const int wh = tid / KSPLIT;           // h index (0..BN-1)
    const int wk = (tid % KSPLIT) * WL;    // k start

    const bool row_ok = (n0 + lm) < n_nodes;

#pragma unroll 1
    for (int chunk = 0; chunk < 8; ++chunk) {
        const float* __restrict__ Ain = (chunk < 4) ? A : B;
        const float* __restrict__ Win = (chunk < 4) ? Wa : Wb;
        const int kb = (chunk & 3) * BK;

        __syncthreads();
        // stage A tile (64 x 32)
        {
            float4 v0 = make_float4(0.f, 0.f, 0.f, 0.f), v1 = v0;
            if (row_ok) {
                const float4* gp = reinterpret_cast<const float4*>(
                    Ain + (size_t)(n0 + lm) * DIM + kb + lk);
                v0 = gp[0];
                v1 = gp[1];
            }
            As[lm][lk + 0] = v0.x; As[lm][lk + 1] = v0.y;
            As[lm][lk + 2] = v0.z; As[lm][lk + 3] = v0.w;
            As[lm][lk + 4] = v1.x; As[lm][lk + 5] = v1.y;
            As[lm][lk + 6] = v1.z; As[lm][lk + 7] = v1.w;
        }
        // stage W tile transposed (32 x BN)
        {
#pragma unroll
            for (int i = 0; i < WL; i += 4) {
                float4 v = *reinterpret_cast<const float4*>(
                    Win + (size_t)wh * DIM + kb + wk + i);
                Ws[wk + i + 0][wh] = v.x;
                Ws[wk + i + 1][wh] = v.y;
                Ws[wk + i + 2][wh] = v.z;
                Ws[wk + i + 3][wh] = v.w;
            }
        }
        __syncthreads();
        // compute 32 K-steps
#pragma unroll
        for (int d = 0; d < BK; ++d) {
            float a[TM];
#pragma unroll
            for (int i = 0; i < TM; ++i) a[i] = As[r * TM + i][d];
            float w[TN];
#pragma unroll
            for (int j = 0; j < TN; j += 4) {
                float4 wv = *reinterpret_cast<const float4*>(&Ws[d][c * TN + j]);
                w[j + 0] = wv.x; w[j + 1] = wv.y;
                w[j + 2] = wv.z; w[j + 3] = wv.w;
            }
#pragma unroll
            for (int i = 0; i < TM; ++i)
#pragma unroll
                for (int j = 0; j < TN; ++j) acc[i][j] += a[i] * w[j];
        }
    }

    // epilogue: bias + optional relu, vectorized store
    float bv[TN];
#pragma unroll
    for (int j = 0; j < TN; ++j) bv[j] = bias[c * TN + j];
#pragma unroll
    for (int i = 0; i < TM; ++i) {
        int n = n0 + r * TM + i;
        if (n >= n_nodes) continue;
#pragma unroll
        for (int j = 0; j < TN; j += 4) {
            float4 o;
            o.x = acc[i][j + 0] + bv[j + 0];
            o.y = acc[i][j + 1] + bv[j + 1];
            o.z = acc[i][j + 2] + bv[j + 2];
            o.w = acc[i][j + 3] + bv[j + 3];
            if (RELU) {
                o.x = fmaxf(o.x, 0.f); o.y = fmaxf(o.y, 0.f);
                o.z = fmaxf(o.z, 0.f); o.w = fmaxf(o.w, 0.f);
            }
            *reinterpret_cast<float4*>(C + (size_t)n * BN + c * TN + j) = o;
        }
    }
}

extern "C" void kernel_launch(void* const* d_in, const int* in_sizes, int n_in,
                              void* d_out, int out_size, void* d_ws, size_t ws_size,
                              hipStream_t stream) {
    const float* x       = (const float*)d_in[0];
    const int*   ei      = (const int*)d_in[1];
    const float* W_rel1  = (const float*)d_in[2];
    const float* W_root1 = (const float*)d_in[3];
    const float* b1      = (const float*)d_in[4];
    const float* W_rel2  = (const float*)d_in[5];
    const float* W_root2 = (const float*)d_in[6];
    const float* b2      = (const float*)d_in[7];

    const int n_edges = in_sizes[1] / 2;
    const int* src = ei;
    const int* dst = ei + n_edges;

    float* agg = (float*)d_ws;                        // [NNODES,128] 25.6 MB (reused)
    float* t   = agg + (size_t)NNODES * DIM;          // [NNODES,128] 25.6 MB
    float* out = (float*)d_out;                       // [NNODES,64]

    const size_t agg_bytes = (size_t)NNODES * DIM * sizeof(float);
    const int scat_blocks = (n_edges * 32 + 255) / 256;
    const int gemm_blocks = (NNODES + 63) / 64;

    // ---- layer 1 ----
    hipMemsetAsync(agg, 0, agg_bytes, stream);
    k_scatter_add<<<scat_blocks, 256, 0, stream>>>(x, src, dst, agg, n_edges);
    k_dual_gemm<128, true><<<gemm_blocks, 256, 0, stream>>>(
        agg, x, W_rel1, W_root1, b1, t, NNODES);

    // ---- layer 2 ----
    hipMemsetAsync(agg, 0, agg_bytes, stream);
    k_scatter_add<<<scat_blocks, 256, 0, stream>>>(t, src, dst, agg, n_edges);
    k_dual_gemm<64, false><<<gemm_blocks, 256, 0, stream>>>(
        agg, t, W_rel2, W_root2, b2, out, NNODES);
}

// Round 3
// 443.431 us; speedup vs baseline: 19.0983x; 6.4851x over previous
//
#include <hip/hip_runtime.h>

#define NNODES 50000
#define DIM 128

// ===========================================================================
// CSR build (per call; graph static within a call, reused by both layers)
// ===========================================================================

// counts[dst[e]]++  (int atomics: ~800k, cheap vs 102.4M float atomics)
__global__ __launch_bounds__(256) void k_hist(
    const int* __restrict__ dst, int* __restrict__ counts, int n_edges)
{
    int e = blockIdx.x * blockDim.x + threadIdx.x;
    if (e >= n_edges) return;
    atomicAdd(&counts[dst[e]], 1);
}

// Exclusive scan of counts[0..n) -> rowptr[0..n], single workgroup of 1024.
// Wave-level shfl scan (6 steps, no sync) + 16-wave LDS combine per chunk.
__global__ __launch_bounds__(1024) void k_scan(
    const int* __restrict__ counts, int* __restrict__ rowptr, int n)
{
    __shared__ int wsum[16];
    __shared__ int running_s;
    const int lane = threadIdx.x & 63;
    const int wid = threadIdx.x >> 6;
    if (threadIdx.x == 0) running_s = 0;
    __syncthreads();
    for (int base = 0; base < n; base += 1024) {
        int i = base + threadIdx.x;
        int v = (i < n) ? counts[i] : 0;
        // wave-inclusive scan
        int s = v;
#pragma unroll
        for (int off = 1; off < 64; off <<= 1) {
            int t = __shfl_up(s, off);
            if (lane >= off) s += t;
        }
        if (lane == 63) wsum[wid] = s;
        __syncthreads();
        if (wid == 0 && lane < 16) {
            int ws = wsum[lane];
#pragma unroll
            for (int off = 1; off < 16; off <<= 1) {
                int t = __shfl_up(ws, off);
                if (lane >= off) ws += t;
            }
            wsum[lane] = ws;   // inclusive wave sums
        }
        __syncthreads();
        int woff = (wid > 0) ? wsum[wid - 1] : 0;
        if (i < n) rowptr[i] = running_s + woff + s - v;   // exclusive
        __syncthreads();
        if (threadIdx.x == 1023) running_s += wsum[15];
        __syncthreads();
    }
    if (threadIdx.x == 0) rowptr[n] = running_s;
}

// srcs_sorted[rowptr[dst[e]] + cursor[dst[e]]++] = src[e]
__global__ __launch_bounds__(256) void k_place(
    const int* __restrict__ src, const int* __restrict__ dst,
    const int* __restrict__ rowptr, int* __restrict__ cursor,
    int* __restrict__ srcs_sorted, int n_edges)
{
    int e = blockIdx.x * blockDim.x + threadIdx.x;
    if (e >= n_edges) return;
    int d = dst[e];
    int pos = rowptr[d] + atomicAdd(&cursor[d], 1);
    srcs_sorted[pos] = src[e];
}

// ===========================================================================
// Gather-sum: agg[n,:] = sum_{e in CSR row n} x[srcs[e], :]
// 32 threads per node (one float4 lane each); each edge = one coalesced
// 512 B row read; x (25.6 MB) is L3-resident. No float atomics.
// ===========================================================================
__global__ __launch_bounds__(256) void k_gather_sum(
    const float* __restrict__ x, const int* __restrict__ rowptr,
    const int* __restrict__ srcs, float* __restrict__ agg)
{
    int g = blockIdx.x * 8 + (threadIdx.x >> 5);  // node, 8 per block
    if (g >= NNODES) return;
    int d4 = threadIdx.x & 31;
    int beg = rowptr[g], end = rowptr[g + 1];
    float4 acc = make_float4(0.f, 0.f, 0.f, 0.f);
    int e = beg;
    // unroll-2: two independent loads in flight
    for (; e + 1 < end; e += 2) {
        int s0 = srcs[e], s1 = srcs[e + 1];
        float4 v0 = reinterpret_cast<const float4*>(x)[(size_t)s0 * 32 + d4];
        float4 v1 = reinterpret_cast<const float4*>(x)[(size_t)s1 * 32 + d4];
        acc.x += v0.x; acc.y += v0.y; acc.z += v0.z; acc.w += v0.w;
        acc.x += v1.x; acc.y += v1.y; acc.z += v1.z; acc.w += v1.w;
    }
    if (e < end) {
        int s0 = srcs[e];
        float4 v0 = reinterpret_cast<const float4*>(x)[(size_t)s0 * 32 + d4];
        acc.x += v0.x; acc.y += v0.y; acc.z += v0.z; acc.w += v0.w;
    }
    reinterpret_cast<float4*>(agg)[(size_t)g * 32 + d4] = acc;
}

// ===========================================================================
// Fused dual GEMM: C[n,h] = act( dot(A[n,:],Wa[h,:]) + dot(B[n,:],Wb[h,:]) + b[h] )
// Chunk loop is "#pragma unroll 1" — full unroll spills (R1: 6 GB scratch).
// ===========================================================================
template <int BN, bool RELU>
__global__ __launch_bounds__(256) void k_dual_gemm(
    const float* __restrict__ A, const float* __restrict__ B,
    const float* __restrict__ Wa, const float* __restrict__ Wb,
    const float* __restrict__ bias, float* __restrict__ C, int n_nodes)
{
    constexpr int BM = 64, BK = 32;
    constexpr int TM = 4;
    constexpr int TN = BN / 16;            // 8 (BN=128) or 4 (BN=64)
    __shared__ float As[BM][BK + 1];
    __shared__ float Ws[BK][BN];

    const int tid = threadIdx.x;
    const int r = tid & 15;
    const int c = tid >> 4;
    const int n0 = blockIdx.x * BM;

    float acc[TM][TN];
#pragma unroll
    for (int i = 0; i < TM; ++i)
#pragma unroll
        for (int j = 0; j < TN; ++j) acc[i][j] = 0.f;

    const int lm = tid >> 2;
    const int lk = (tid & 3) * 8;
    constexpr int WL = (BK * BN) / 256;
    constexpr int KSPLIT = BK / WL;
    const int wh = tid / KSPLIT;
    const int wk = (tid % KSPLIT) * WL;

    const bool row_ok = (n0 + lm) < n_nodes;

#pragma unroll 1
    for (int chunk = 0; chunk < 8; ++chunk) {
        const float* __restrict__ Ain = (chunk < 4) ? A : B;
        const float* __restrict__ Win = (chunk < 4) ? Wa : Wb;
        const int kb = (chunk & 3) * BK;

        __syncthreads();
        {
            float4 v0 = make_float4(0.f, 0.f, 0.f, 0.f), v1 = v0;
            if (row_ok) {
                const float4* gp = reinterpret_cast<const float4*>(
                    Ain + (size_t)(n0 + lm) * DIM + kb + lk);
                v0 = gp[0];
                v1 = gp[1];
            }
            As[lm][lk + 0] = v0.x; As[lm][lk + 1] = v0.y;
            As[lm][lk + 2] = v0.z; As[lm][lk + 3] = v0.w;
            As[lm][lk + 4] = v1.x; As[lm][lk + 5] = v1.y;
            As[lm][lk + 6] = v1.z; As[lm][lk + 7] = v1.w;
        }
        {
#pragma unroll
            for (int i = 0; i < WL; i += 4) {
                float4 v = *reinterpret_cast<const float4*>(
                    Win + (size_t)wh * DIM + kb + wk + i);
                Ws[wk + i + 0][wh] = v.x;
                Ws[wk + i + 1][wh] = v.y;
                Ws[wk + i + 2][wh] = v.z;
                Ws[wk + i + 3][wh] = v.w;
            }
        }
        __syncthreads();
#pragma unroll
        for (int d = 0; d < BK; ++d) {
            float a[TM];
#pragma unroll
            for (int i = 0; i < TM; ++i) a[i] = As[r * TM + i][d];
            float w[TN];
#pragma unroll
            for (int j = 0; j < TN; j += 4) {
                float4 wv = *reinterpret_cast<const float4*>(&Ws[d][c * TN + j]);
                w[j + 0] = wv.x; w[j + 1] = wv.y;
                w[j + 2] = wv.z; w[j + 3] = wv.w;
            }
#pragma unroll
            for (int i = 0; i < TM; ++i)
#pragma unroll
                for (int j = 0; j < TN; ++j) acc[i][j] += a[i] * w[j];
        }
    }

    float bv[TN];
#pragma unroll
    for (int j = 0; j < TN; ++j) bv[j] = bias[c * TN + j];
#pragma unroll
    for (int i = 0; i < TM; ++i) {
        int n = n0 + r * TM + i;
        if (n >= n_nodes) continue;
#pragma unroll
        for (int j = 0; j < TN; j += 4) {
            float4 o;
            o.x = acc[i][j + 0] + bv[j + 0];
            o.y = acc[i][j + 1] + bv[j + 1];
            o.z = acc[i][j + 2] + bv[j + 2];
            o.w = acc[i][j + 3] + bv[j + 3];
            if (RELU) {
                o.x = fmaxf(o.x, 0.f); o.y = fmaxf(o.y, 0.f);
                o.z = fmaxf(o.z, 0.f); o.w = fmaxf(o.w, 0.f);
            }
            *reinterpret_cast<float4*>(C + (size_t)n * BN + c * TN + j) = o;
        }
    }
}

extern "C" void kernel_launch(void* const* d_in, const int* in_sizes, int n_in,
                              void* d_out, int out_size, void* d_ws, size_t ws_size,
                              hipStream_t stream) {
    const float* x       = (const float*)d_in[0];
    const int*   ei      = (const int*)d_in[1];   // harness passes ints as int32
    const float* W_rel1  = (const float*)d_in[2];
    const float* W_root1 = (const float*)d_in[3];
    const float* b1      = (const float*)d_in[4];
    const float* W_rel2  = (const float*)d_in[5];
    const float* W_root2 = (const float*)d_in[6];
    const float* b2      = (const float*)d_in[7];

    const int n_edges = in_sizes[1] / 2;
    const int* src = ei;
    const int* dst = ei + n_edges;

    // workspace layout
    float* agg  = (float*)d_ws;                           // 6.4M floats
    float* t    = agg + (size_t)NNODES * DIM;             // 6.4M floats
    int* rowptr = (int*)(t + (size_t)NNODES * DIM);       // NNODES+1
    int* cursor = rowptr + (NNODES + 1);                  // NNODES
    int* srcs   = cursor + NNODES;                        // n_edges

    float* out = (float*)d_out;

    const int eblocks = (n_edges + 255) / 256;
    const int gblocks = (NNODES + 7) / 8;
    const int gemm_blocks = (NNODES + 63) / 64;

    // ---- CSR build (once; reused by both layers) ----
    hipMemsetAsync(cursor, 0, NNODES * sizeof(int), stream);
    k_hist<<<eblocks, 256, 0, stream>>>(dst, cursor, n_edges);
    k_scan<<<1, 1024, 0, stream>>>(cursor, rowptr, NNODES);
    hipMemsetAsync(cursor, 0, NNODES * sizeof(int), stream);
    k_place<<<eblocks, 256, 0, stream>>>(src, dst, rowptr, cursor, srcs, n_edges);

    // ---- layer 1 ----
    k_gather_sum<<<gblocks, 256, 0, stream>>>(x, rowptr, srcs, agg);
    k_dual_gemm<128, true><<<gemm_blocks, 256, 0, stream>>>(
        agg, x, W_rel1, W_root1, b1, t, NNODES);

    // ---- layer 2 ----
    k_gather_sum<<<gblocks, 256, 0, stream>>>(t, rowptr, srcs, agg);
    k_dual_gemm<64, false><<<gemm_blocks, 256, 0, stream>>>(
        agg, t, W_rel2, W_root2, b2, out, NNODES);
}